// Round 2
// baseline (303.079 us; speedup 1.0000x reference)
//
#include <hip/hip_runtime.h>
#include <stdint.h>

#define PRNG_MODE 0

#define BB 64
#define NC 1000       // customers per instance
#define KC 10         // clusters

__host__ __device__ inline void threefry2x32(uint32_t k0, uint32_t k1,
                                             uint32_t x0, uint32_t x1,
                                             uint32_t* o0, uint32_t* o1) {
  uint32_t k2 = k0 ^ k1 ^ 0x1BD11BDAu;
  x0 += k0; x1 += k1;
#define TF_R(R) { x0 += x1; x1 = (x1 << (R)) | (x1 >> (32 - (R))); x1 ^= x0; }
  TF_R(13) TF_R(15) TF_R(26) TF_R(6)
  x0 += k1; x1 += k2 + 1u;
  TF_R(17) TF_R(29) TF_R(16) TF_R(24)
  x0 += k2; x1 += k0 + 2u;
  TF_R(13) TF_R(15) TF_R(26) TF_R(6)
  x0 += k0; x1 += k1 + 3u;
  TF_R(17) TF_R(29) TF_R(16) TF_R(24)
  x0 += k1; x1 += k2 + 4u;
  TF_R(13) TF_R(15) TF_R(26) TF_R(6)
  x0 += k2; x1 += k0 + 5u;
#undef TF_R
  *o0 = x0; *o1 = x1;
}

__device__ inline uint32_t rand_bits(uint32_t ks0, uint32_t ks1, uint32_t p) {
  uint32_t a, b; threefry2x32(ks0, ks1, 0u, p, &a, &b); return b;
}

// ---------------------------------------------------------------------------
// Fused: sample (gumbel argmax) + logprob sum + grouping + capacity split +
//        per-route NN distance. One block per instance.
// ---------------------------------------------------------------------------
__global__ __launch_bounds__(256) void k_main(
    const float* __restrict__ logits,    // (64,1001,10)
    const float* __restrict__ coords,    // (64,1001,2)
    const float* __restrict__ demands,   // (64,1001)
    const float* __restrict__ capacity,  // (64,)
    uint32_t ks0, uint32_t ks1,
    double* __restrict__ lp,             // (64,)
    double* __restrict__ dist) {         // (64,)
  int b = blockIdx.x;
  int tid = threadIdx.x;
  const float TINY = 1.1754943508222875e-38f;

  __shared__ uint8_t sa[NC];                 // sampled cluster per customer
  __shared__ float memx[NC], memy[NC], memd[NC];  // member-order compact
  __shared__ uint16_t scnt[KC][256];         // per-thread-chunk counts -> prefix
  __shared__ uint16_t rs[NC], rl[NC];        // route start/len (cluster-local)
  __shared__ uint8_t vis[NC];
  __shared__ int mc[KC], mbase[KC], rc[KC];
  __shared__ float sdepot[2];
  __shared__ double red[256];

  // ---- 1. sampling + logprob (identical math to passing version) ----
  double lacc = 0.0;
  for (int n = tid; n < NC; n += 256) {
    const float* lrow = logits + ((size_t)b * 1001 + (size_t)(n + 1)) * KC;
    float xs[KC];
#pragma unroll
    for (int k = 0; k < KC; ++k) xs[k] = lrow[k];
    uint32_t pbase = (uint32_t)(b * NC + n) * (uint32_t)KC;
    int best_k = 0;
    float best_v = -INFINITY;
    float xmax = -INFINITY;
#pragma unroll
    for (int k = 0; k < KC; ++k) {
      uint32_t bits = rand_bits(ks0, ks1, pbase + (uint32_t)k);
      float f = __uint_as_float((bits >> 9) | 0x3f800000u) - 1.0f;
      float u = (f > 0.0f) ? f : TINY;
      float g = -logf(-logf(u));
      float v = g + xs[k];
      if (v > best_v) { best_v = v; best_k = k; }
      xmax = fmaxf(xmax, xs[k]);
    }
    float s = 0.0f;
#pragma unroll
    for (int k = 0; k < KC; ++k) s += expf(xs[k] - xmax);
    float slp = (xs[best_k] - xmax) - logf(s);
    lacc += (double)slp;
    sa[n] = (uint8_t)best_k;
  }
  if (tid == 0) {
    sdepot[0] = coords[(size_t)b * 1001 * 2 + 0];
    sdepot[1] = coords[(size_t)b * 1001 * 2 + 1];
  }
  for (int i = tid; i < NC; i += 256) vis[i] = 0;

  // reduce logprob now (reuses red before dist reduction)
  red[tid] = lacc;
  __syncthreads();
  for (int off = 128; off > 0; off >>= 1) {
    if (tid < off) red[tid] += red[tid + off];
    __syncthreads();
  }
  if (tid == 0) lp[b] = red[0];

  // ---- 2. stable grouping: chunk of 4 customers per thread ----
  int i0 = tid * 4;
  int a0 = 0xFF, a1 = 0xFF, a2 = 0xFF, a3 = 0xFF;
  float x0f = 0, y0f = 0, d0f = 0, x1f = 0, y1f = 0, d1f = 0;
  float x2f = 0, y2f = 0, d2f = 0, x3f = 0, y3f = 0, d3f = 0;
  {
    const float* cb = coords + (size_t)b * 1001 * 2;
    const float* db = demands + (size_t)b * 1001;
    if (i0 + 0 < NC) { a0 = sa[i0 + 0]; x0f = cb[(i0 + 1) * 2]; y0f = cb[(i0 + 1) * 2 + 1]; d0f = db[i0 + 1]; }
    if (i0 + 1 < NC) { a1 = sa[i0 + 1]; x1f = cb[(i0 + 2) * 2]; y1f = cb[(i0 + 2) * 2 + 1]; d1f = db[i0 + 2]; }
    if (i0 + 2 < NC) { a2 = sa[i0 + 2]; x2f = cb[(i0 + 3) * 2]; y2f = cb[(i0 + 3) * 2 + 1]; d2f = db[i0 + 3]; }
    if (i0 + 3 < NC) { a3 = sa[i0 + 3]; x3f = cb[(i0 + 4) * 2]; y3f = cb[(i0 + 4) * 2 + 1]; d3f = db[i0 + 4]; }
  }
#pragma unroll
  for (int k = 0; k < KC; ++k) {
    int c = (a0 == k) + (a1 == k) + (a2 == k) + (a3 == k);
    scnt[k][tid] = (uint16_t)c;
  }
  __syncthreads();
  // exclusive prefix per cluster (10 lanes, sequential LDS reads pipeline)
  if (tid < KC) {
    int run = 0;
    for (int t = 0; t < 256; ++t) {
      int v = scnt[tid][t];
      scnt[tid][t] = (uint16_t)run;
      run += v;
    }
    mc[tid] = run;
  }
  __syncthreads();
  if (tid == 0) {
    int s = 0;
    for (int k = 0; k < KC; ++k) { mbase[k] = s; s += mc[k]; }
  }
  __syncthreads();
  // scatter into member order (stable: index order within cluster)
#pragma unroll
  for (int k = 0; k < KC; ++k) {
    int pos = mbase[k] + (int)scnt[k][tid];
    if (a0 == k) { memx[pos] = x0f; memy[pos] = y0f; memd[pos] = d0f; pos++; }
    if (a1 == k) { memx[pos] = x1f; memy[pos] = y1f; memd[pos] = d1f; pos++; }
    if (a2 == k) { memx[pos] = x2f; memy[pos] = y2f; memd[pos] = d2f; pos++; }
    if (a3 == k) { memx[pos] = x3f; memy[pos] = y3f; memd[pos] = d3f; pos++; }
  }
  __syncthreads();

  // ---- 3. capacity split per cluster (exact f32 scan semantics) ----
  float cap = capacity[b];
  if (tid < KC) {
    int base = mbase[tid], M = mc[tid];
    int r = 0, cur = 0;
    float load = 0.0f;
    bool ne = false;
    for (int j0 = 0; j0 < M; j0 += 4) {
      // 4-ahead LDS loads (independent addresses -> overlap latency)
      float dd0 = memd[base + j0];
      float dd1 = (j0 + 1 < M) ? memd[base + j0 + 1] : 0.0f;
      float dd2 = (j0 + 2 < M) ? memd[base + j0 + 2] : 0.0f;
      float dd3 = (j0 + 3 < M) ? memd[base + j0 + 3] : 0.0f;
#define SPLIT_STEP(dd, jj)                                                   \
      if (j0 + jj < M) {                                                     \
        float d = dd;                                                        \
        if (ne && (load + d > cap)) {                                        \
          rs[base + r] = (uint16_t)cur; rl[base + r] = (uint16_t)(j0 + jj - cur); \
          r++; cur = j0 + jj; load = d;                                      \
        } else load += d;                                                    \
        ne = true;                                                           \
      }
      SPLIT_STEP(dd0, 0) SPLIT_STEP(dd1, 1) SPLIT_STEP(dd2, 2) SPLIT_STEP(dd3, 3)
#undef SPLIT_STEP
    }
    if (ne) { rs[base + r] = (uint16_t)cur; rl[base + r] = (uint16_t)(M - cur); r++; }
    rc[tid] = r;
  }
  __syncthreads();

  // ---- 4. NN tour per route (disjoint spans -> no races) ----
  double acc = 0.0;
  float dx0 = sdepot[0], dy0 = sdepot[1];
  for (int k = 0; k < KC; ++k) {
    int base = mbase[k], R = rc[k];
    for (int r = tid; r < R; r += 256) {
      int s = base + (int)rs[base + r];
      int L = (int)rl[base + r];
      float px = dx0, py = dy0, racc = 0.0f;
      for (int step = 0; step < L; ++step) {
        float best = INFINITY; int bj = -1;
        for (int j = s; j < s + L; ++j) {
          if (!vis[j]) {
            float ddx = memx[j] - px, ddy = memy[j] - py;
            float d = sqrtf(ddx * ddx + ddy * ddy);
            if (d < best) { best = d; bj = j; }   // min index on ties
          }
        }
        vis[bj] = 1;
        px = memx[bj]; py = memy[bj];
        racc += best;                              // f32, scan order
      }
      float ddx = px - dx0, ddy = py - dy0;
      racc += sqrtf(ddx * ddx + ddy * ddy);
      acc += (double)racc;
    }
  }
  red[tid] = acc;
  __syncthreads();
  for (int off = 128; off > 0; off >>= 1) {
    if (tid < off) red[tid] += red[tid + off];
    __syncthreads();
  }
  if (tid == 0) dist[b] = red[0];
}

// ---------------------------------------------------------------------------
// Final: baseline + REINFORCE loss
// ---------------------------------------------------------------------------
__global__ void k_final(const double* __restrict__ lp,
                        const double* __restrict__ dist,
                        float* __restrict__ out) {
  if (threadIdx.x == 0 && blockIdx.x == 0) {
    float df[BB], lf[BB];
    double sum = 0.0;
    for (int i = 0; i < BB; ++i) {
      df[i] = (float)dist[i];
      lf[i] = (float)lp[i];
      sum += (double)df[i];
    }
    double mean = sum / (double)BB;
    float meanf = (float)mean;
    double loss = 0.0;
    for (int i = 0; i < BB; ++i)
      loss += ((double)df[i] - (double)meanf) * (double)lf[i];
    loss /= (double)BB;
    out[0] = (float)loss;
    out[1] = (float)mean;
  }
}

extern "C" void kernel_launch(void* const* d_in, const int* in_sizes, int n_in,
                              void* d_out, int out_size, void* d_ws, size_t ws_size,
                              hipStream_t stream) {
  const float* logits   = (const float*)d_in[0];  // (64,1001,10)
  const float* coords   = (const float*)d_in[1];  // (64,1001,2)
  const float* demands  = (const float*)d_in[2];  // (64,1001)
  const float* capacity = (const float*)d_in[3];  // (64,)

  uint8_t* ws  = (uint8_t*)d_ws;
  double* lp   = (double*)ws;             // 512 B
  double* dist = (double*)(ws + 1024);    // 512 B

  uint32_t ks0, ks1;
  threefry2x32(0u, 42u, 0u, 0u, &ks0, &ks1);   // fold_in(key(42), 0)

  k_main<<<dim3(BB), dim3(256), 0, stream>>>(logits, coords, demands, capacity,
                                             ks0, ks1, lp, dist);
  k_final<<<dim3(1), dim3(64), 0, stream>>>(lp, dist, (float*)d_out);
}

// Round 3
// 70.978 us; speedup vs baseline: 4.2701x; 4.2701x over previous
//
#include <hip/hip_runtime.h>
#include <stdint.h>

#define BB 64
#define NC 1000       // customers per instance
#define KC 10         // clusters
#define MAXR 512      // routes per instance upper bound (realistic max ~140)
#define WPB_B 8       // blocks per instance in NN kernel

__host__ __device__ inline void threefry2x32(uint32_t k0, uint32_t k1,
                                             uint32_t x0, uint32_t x1,
                                             uint32_t* o0, uint32_t* o1) {
  uint32_t k2 = k0 ^ k1 ^ 0x1BD11BDAu;
  x0 += k0; x1 += k1;
#define TF_R(R) { x0 += x1; x1 = (x1 << (R)) | (x1 >> (32 - (R))); x1 ^= x0; }
  TF_R(13) TF_R(15) TF_R(26) TF_R(6)
  x0 += k1; x1 += k2 + 1u;
  TF_R(17) TF_R(29) TF_R(16) TF_R(24)
  x0 += k2; x1 += k0 + 2u;
  TF_R(13) TF_R(15) TF_R(26) TF_R(6)
  x0 += k0; x1 += k1 + 3u;
  TF_R(17) TF_R(29) TF_R(16) TF_R(24)
  x0 += k1; x1 += k2 + 4u;
  TF_R(13) TF_R(15) TF_R(26) TF_R(6)
  x0 += k2; x1 += k0 + 5u;
#undef TF_R
  *o0 = x0; *o1 = x1;
}

__device__ inline uint32_t rand_bits(uint32_t ks0, uint32_t ks1, uint32_t p) {
  uint32_t a, b; threefry2x32(ks0, ks1, 0u, p, &a, &b); return b;
}

// ---------------------------------------------------------------------------
// Kernel A: sampling + logprob + stable grouping + capacity split.
// Outputs: gxy (member-order coords), groutes (packed start<<16|len, compact),
//          rcount, lp. One block per instance.
// ---------------------------------------------------------------------------
__global__ __launch_bounds__(256) void k_prep(
    const float* __restrict__ logits,    // (64,1001,10)
    const float* __restrict__ coords,    // (64,1001,2)
    const float* __restrict__ demands,   // (64,1001)
    const float* __restrict__ capacity,  // (64,)
    uint32_t ks0, uint32_t ks1,
    float2* __restrict__ gxy,            // (64,1000)
    uint32_t* __restrict__ groutes,      // (64,MAXR)
    int* __restrict__ rcount,            // (64,)
    double* __restrict__ lp) {           // (64,)
  int b = blockIdx.x;
  int tid = threadIdx.x;
  int lane = tid & 63, wave = tid >> 6;
  const float TINY = 1.1754943508222875e-38f;

  __shared__ uint8_t sa[NC];
  __shared__ float memx[NC], memy[NC], memd[NC];
  __shared__ uint16_t rs_[NC], rl_[NC];
  __shared__ int wsum[4][KC];
  __shared__ int mc[KC], mbase[KC], rc[KC], rbase[KC];
  __shared__ double red[256];

  // ---- 1. sampling + logprob (byte-identical math to passing rounds) ----
  double lacc = 0.0;
  for (int n = tid; n < NC; n += 256) {
    const float* lrow = logits + ((size_t)b * 1001 + (size_t)(n + 1)) * KC;
    float xs[KC];
#pragma unroll
    for (int k = 0; k < KC; ++k) xs[k] = lrow[k];
    uint32_t pbase = (uint32_t)(b * NC + n) * (uint32_t)KC;
    int best_k = 0;
    float best_v = -INFINITY;
    float xmax = -INFINITY;
#pragma unroll
    for (int k = 0; k < KC; ++k) {
      uint32_t bits = rand_bits(ks0, ks1, pbase + (uint32_t)k);
      float f = __uint_as_float((bits >> 9) | 0x3f800000u) - 1.0f;
      float u = (f > 0.0f) ? f : TINY;
      float g = -logf(-logf(u));
      float v = g + xs[k];
      if (v > best_v) { best_v = v; best_k = k; }
      xmax = fmaxf(xmax, xs[k]);
    }
    float s = 0.0f;
#pragma unroll
    for (int k = 0; k < KC; ++k) s += expf(xs[k] - xmax);
    float slp = (xs[best_k] - xmax) - logf(s);
    lacc += (double)slp;
    sa[n] = (uint8_t)best_k;
  }
  red[tid] = lacc;
  __syncthreads();                 // also publishes sa[]
  for (int off = 128; off > 0; off >>= 1) {
    if (tid < off) red[tid] += red[tid + off];
    __syncthreads();
  }
  if (tid == 0) lp[b] = red[0];

  // ---- 2. per-thread chunk of 4 customers ----
  int i0 = tid * 4;
  int a0 = 0xFF, a1 = 0xFF, a2 = 0xFF, a3 = 0xFF;
  float x0f = 0, y0f = 0, d0f = 0, x1f = 0, y1f = 0, d1f = 0;
  float x2f = 0, y2f = 0, d2f = 0, x3f = 0, y3f = 0, d3f = 0;
  {
    const float* cb = coords + (size_t)b * 1001 * 2;
    const float* db = demands + (size_t)b * 1001;
    if (i0 + 0 < NC) { a0 = sa[i0 + 0]; x0f = cb[(i0 + 1) * 2]; y0f = cb[(i0 + 1) * 2 + 1]; d0f = db[i0 + 1]; }
    if (i0 + 1 < NC) { a1 = sa[i0 + 1]; x1f = cb[(i0 + 2) * 2]; y1f = cb[(i0 + 2) * 2 + 1]; d1f = db[i0 + 2]; }
    if (i0 + 2 < NC) { a2 = sa[i0 + 2]; x2f = cb[(i0 + 3) * 2]; y2f = cb[(i0 + 3) * 2 + 1]; d2f = db[i0 + 3]; }
    if (i0 + 3 < NC) { a3 = sa[i0 + 3]; x3f = cb[(i0 + 4) * 2]; y3f = cb[(i0 + 4) * 2 + 1]; d3f = db[i0 + 4]; }
  }
  int cnt[KC], excl[KC];
#pragma unroll
  for (int k = 0; k < KC; ++k)
    cnt[k] = (a0 == k) + (a1 == k) + (a2 == k) + (a3 == k);

  // ---- 3. parallel exclusive prefix per cluster (shfl scan + wave partials) ----
#pragma unroll
  for (int k = 0; k < KC; ++k) {
    int x = cnt[k];
#pragma unroll
    for (int off = 1; off < 64; off <<= 1) {
      int v = __shfl_up(x, off);
      if (lane >= off) x += v;
    }
    if (lane == 63) wsum[wave][k] = x;
    excl[k] = x - cnt[k];
  }
  __syncthreads();
  if (tid == 0) {
    int s = 0;
    for (int k = 0; k < KC; ++k) {
      int t = wsum[0][k] + wsum[1][k] + wsum[2][k] + wsum[3][k];
      mc[k] = t; mbase[k] = s; s += t;
    }
  }
  __syncthreads();
#pragma unroll
  for (int k = 0; k < KC; ++k) {
    int base = mbase[k];
    for (int w = 0; w < wave; ++w) base += wsum[w][k];
    excl[k] += base;
  }

  // ---- 4. stable scatter into member order ----
#pragma unroll
  for (int k = 0; k < KC; ++k) {
    int pos = excl[k];
    if (a0 == k) { memx[pos] = x0f; memy[pos] = y0f; memd[pos] = d0f; pos++; }
    if (a1 == k) { memx[pos] = x1f; memy[pos] = y1f; memd[pos] = d1f; pos++; }
    if (a2 == k) { memx[pos] = x2f; memy[pos] = y2f; memd[pos] = d2f; pos++; }
    if (a3 == k) { memx[pos] = x3f; memy[pos] = y3f; memd[pos] = d3f; pos++; }
  }
  __syncthreads();

  // ---- 5a. publish member-order coords (coalesced float2 stores) ----
  for (int i = tid; i < NC; i += 256)
    gxy[(size_t)b * NC + i] = make_float2(memx[i], memy[i]);

  // ---- 5b. capacity split per cluster (exact f32 scan semantics) ----
  float cap = capacity[b];
  if (tid < KC) {
    int base = mbase[tid], M = mc[tid];
    int r = 0, cur = 0;
    float load = 0.0f;
    bool ne = false;
    for (int j0 = 0; j0 < M; j0 += 4) {
      float dd0 = memd[base + j0];
      float dd1 = (j0 + 1 < M) ? memd[base + j0 + 1] : 0.0f;
      float dd2 = (j0 + 2 < M) ? memd[base + j0 + 2] : 0.0f;
      float dd3 = (j0 + 3 < M) ? memd[base + j0 + 3] : 0.0f;
#define SPLIT_STEP(dd, jj)                                                    \
      if (j0 + jj < M) {                                                      \
        float d = dd;                                                         \
        if (ne && (load + d > cap)) {                                         \
          rs_[base + r] = (uint16_t)cur; rl_[base + r] = (uint16_t)(j0 + jj - cur); \
          r++; cur = j0 + jj; load = d;                                       \
        } else load += d;                                                     \
        ne = true;                                                            \
      }
      SPLIT_STEP(dd0, 0) SPLIT_STEP(dd1, 1) SPLIT_STEP(dd2, 2) SPLIT_STEP(dd3, 3)
#undef SPLIT_STEP
    }
    if (ne) { rs_[base + r] = (uint16_t)cur; rl_[base + r] = (uint16_t)(M - cur); r++; }
    rc[tid] = r;
  }
  __syncthreads();
  if (tid == 0) {
    int s = 0;
    for (int k = 0; k < KC; ++k) { rbase[k] = s; s += rc[k]; }
    rcount[b] = (s < MAXR) ? s : MAXR;
  }
  __syncthreads();

  // ---- 6. compact route table to global ----
  if (tid < KC) {
    int k = tid, base = mbase[k];
    for (int r = 0; r < rc[k]; ++r) {
      int slot = rbase[k] + r;
      if (slot < MAXR)
        groutes[(size_t)b * MAXR + slot] =
            ((uint32_t)(base + rs_[base + r]) << 16) | (uint32_t)rl_[base + r];
    }
  }
}

// ---------------------------------------------------------------------------
// Kernel B: one WAVE per route, members in registers, shfl-reduce argmin.
// Bit-identical winner + f32 accumulation order vs the serial reference scan.
// ---------------------------------------------------------------------------
__global__ __launch_bounds__(256) void k_nn(
    const float* __restrict__ coords,     // (64,1001,2) for depot
    const float2* __restrict__ gxy,       // (64,1000) member order
    const uint32_t* __restrict__ groutes, // (64,MAXR)
    const int* __restrict__ rcount,       // (64,)
    float* __restrict__ rdist) {          // (64,MAXR)
  int b = blockIdx.x / WPB_B;
  int sub = blockIdx.x % WPB_B;
  int lane = threadIdx.x & 63;
  int wi = sub * 4 + (threadIdx.x >> 6);       // wave index within instance, 0..31

  float dx0 = coords[(size_t)b * 1001 * 2];
  float dy0 = coords[(size_t)b * 1001 * 2 + 1];
  int R = rcount[b];

  for (int r = wi; r < R; r += WPB_B * 4) {
    uint32_t pk = groutes[(size_t)b * MAXR + r];
    int start = (int)(pk >> 16);
    int L = (int)(pk & 0xFFFFu);

    // lane j holds member slots j, j+64, j+128, j+192 (slot order = orig index order)
    float mx0 = 0, my0 = 0, mx1 = 0, my1 = 0, mx2 = 0, my2 = 0, mx3 = 0, my3 = 0;
    uint32_t vis = 0;
#define LOADC(c, MX, MY)                                                      \
    { int s = (c) * 64 + lane;                                                \
      if (s < L) { float2 v = gxy[(size_t)b * NC + start + s]; MX = v.x; MY = v.y; } \
      else vis |= (1u << (c)); }
    LOADC(0, mx0, my0) LOADC(1, mx1, my1) LOADC(2, mx2, my2) LOADC(3, mx3, my3)
#undef LOADC

    float px = dx0, py = dy0, racc = 0.0f;
    for (int step = 0; step < L; ++step) {
      float bd = INFINITY; int bc = -1;
#define CAND(c, MX, MY)                                                       \
      if (!(vis & (1u << (c)))) {                                             \
        float ddx = MX - px, ddy = MY - py;                                   \
        float d = sqrtf(ddx * ddx + ddy * ddy);                               \
        if (d < bd) { bd = d; bc = (c); }                                     \
      }
      CAND(0, mx0, my0) CAND(1, mx1, my1) CAND(2, mx2, my2) CAND(3, mx3, my3)
#undef CAND
      unsigned long long comb = (bc < 0)
          ? ~0ull
          : (((unsigned long long)__float_as_uint(bd)) << 32) |
            (unsigned)(bc * 64 + lane);
#pragma unroll
      for (int m = 1; m < 64; m <<= 1) {
        unsigned long long o = __shfl_xor(comb, m);
        comb = (o < comb) ? o : comb;
      }
      if (comb == ~0ull) break;   // can't happen for well-formed routes
      int slot = (int)(comb & 0xFFFFFFFFull);
      float best = __uint_as_float((uint32_t)(comb >> 32));
      int src = slot & 63, cu = slot >> 6;
      if (src == lane) vis |= (1u << cu);
      float cx, cy;
      switch (cu) {
        case 0: cx = mx0; cy = my0; break;
        case 1: cx = mx1; cy = my1; break;
        case 2: cx = mx2; cy = my2; break;
        default: cx = mx3; cy = my3; break;
      }
      px = __shfl(cx, src);
      py = __shfl(cy, src);
      racc += best;                     // f32, step order == reference scan order
    }
    float ddx = px - dx0, ddy = py - dy0;
    racc += sqrtf(ddx * ddx + ddy * ddy);   // return-to-depot leg
    if (lane == 0) rdist[(size_t)b * MAXR + r] = racc;
  }
}

// ---------------------------------------------------------------------------
// Kernel C: per-instance route-distance sum + baseline + REINFORCE loss
// ---------------------------------------------------------------------------
__global__ __launch_bounds__(64) void k_final(
    const double* __restrict__ lp,
    const float* __restrict__ rdist,
    const int* __restrict__ rcount,
    float* __restrict__ out) {
  __shared__ double sdist[BB];
  int tid = threadIdx.x;
  {
    int R = rcount[tid];
    const float* rd = rdist + (size_t)tid * MAXR;
    double s0 = 0, s1 = 0, s2 = 0, s3 = 0;
    int r = 0;
    for (; r + 4 <= R; r += 4) {
      s0 += (double)rd[r + 0]; s1 += (double)rd[r + 1];
      s2 += (double)rd[r + 2]; s3 += (double)rd[r + 3];
    }
    for (; r < R; ++r) s0 += (double)rd[r];
    sdist[tid] = (s0 + s1) + (s2 + s3);
  }
  __syncthreads();
  if (tid == 0) {
    float df[BB], lf[BB];
    double sum = 0.0;
    for (int i = 0; i < BB; ++i) {
      df[i] = (float)sdist[i];
      lf[i] = (float)lp[i];
      sum += (double)df[i];
    }
    double mean = sum / (double)BB;
    float meanf = (float)mean;
    double loss = 0.0;
    for (int i = 0; i < BB; ++i)
      loss += ((double)df[i] - (double)meanf) * (double)lf[i];
    loss /= (double)BB;
    out[0] = (float)loss;
    out[1] = (float)mean;
  }
}

extern "C" void kernel_launch(void* const* d_in, const int* in_sizes, int n_in,
                              void* d_out, int out_size, void* d_ws, size_t ws_size,
                              hipStream_t stream) {
  const float* logits   = (const float*)d_in[0];  // (64,1001,10)
  const float* coords   = (const float*)d_in[1];  // (64,1001,2)
  const float* demands  = (const float*)d_in[2];  // (64,1001)
  const float* capacity = (const float*)d_in[3];  // (64,)

  uint8_t* ws = (uint8_t*)d_ws;
  // layout (all offsets 512B-aligned):
  float2*   gxy     = (float2*)(ws);                        // 512000 B
  float*    rdist   = (float*)(ws + 512000);                // 131072 B
  uint32_t* groutes = (uint32_t*)(ws + 512000 + 131072);    // 131072 B
  int*      rcount  = (int*)(ws + 512000 + 262144);         // 256 B
  double*   lp      = (double*)(ws + 512000 + 262144 + 512);// 512 B

  uint32_t ks0, ks1;
  threefry2x32(0u, 42u, 0u, 0u, &ks0, &ks1);   // fold_in(key(42), 0)

  k_prep<<<dim3(BB), dim3(256), 0, stream>>>(logits, coords, demands, capacity,
                                             ks0, ks1, gxy, groutes, rcount, lp);
  k_nn<<<dim3(BB * WPB_B), dim3(256), 0, stream>>>(coords, gxy, groutes, rcount, rdist);
  k_final<<<dim3(1), dim3(64), 0, stream>>>(lp, rdist, rcount, (float*)d_out);
}

// Round 5
// 47.520 us; speedup vs baseline: 6.3779x; 1.4936x over previous
//
#include <hip/hip_runtime.h>
#include <stdint.h>

#define BB 64
#define NC 1000       // customers per instance
#define KC 10         // clusters
#define MAXR 512      // routes per instance upper bound (realistic max ~140)
#define WPB_B 16      // blocks per instance in NN kernel (16 groups each)

__host__ __device__ inline void threefry2x32(uint32_t k0, uint32_t k1,
                                             uint32_t x0, uint32_t x1,
                                             uint32_t* o0, uint32_t* o1) {
  uint32_t k2 = k0 ^ k1 ^ 0x1BD11BDAu;
  x0 += k0; x1 += k1;
#define TF_R(R) { x0 += x1; x1 = (x1 << (R)) | (x1 >> (32 - (R))); x1 ^= x0; }
  TF_R(13) TF_R(15) TF_R(26) TF_R(6)
  x0 += k1; x1 += k2 + 1u;
  TF_R(17) TF_R(29) TF_R(16) TF_R(24)
  x0 += k2; x1 += k0 + 2u;
  TF_R(13) TF_R(15) TF_R(26) TF_R(6)
  x0 += k0; x1 += k1 + 3u;
  TF_R(17) TF_R(29) TF_R(16) TF_R(24)
  x0 += k1; x1 += k2 + 4u;
  TF_R(13) TF_R(15) TF_R(26) TF_R(6)
  x0 += k2; x1 += k0 + 5u;
#undef TF_R
  *o0 = x0; *o1 = x1;
}

__device__ inline uint32_t rand_bits(uint32_t ks0, uint32_t ks1, uint32_t p) {
  uint32_t a, b; threefry2x32(ks0, ks1, 0u, p, &a, &b); return b;
}

// ---------------------------------------------------------------------------
// Kernel S: one thread per customer — gumbel-argmax sample + logprob.
// ---------------------------------------------------------------------------
__global__ __launch_bounds__(256) void k_sample(
    const float* __restrict__ logits,   // (64,1001,10)
    uint32_t ks0, uint32_t ks1,
    uint8_t* __restrict__ assign,       // (64,1000)
    float* __restrict__ slp) {          // (64,1000)
  int gid = blockIdx.x * 256 + threadIdx.x;
  if (gid >= BB * NC) return;
  int b = gid / NC, n = gid - b * NC;
  const float TINY = 1.1754943508222875e-38f;

  const float* lrow = logits + ((size_t)b * 1001 + (size_t)(n + 1)) * KC;
  float xs[KC];
#pragma unroll
  for (int k = 0; k < KC; ++k) xs[k] = lrow[k];
  uint32_t pbase = (uint32_t)gid * (uint32_t)KC;
  int best_k = 0;
  float best_v = -INFINITY;
  float xmax = -INFINITY;
#pragma unroll
  for (int k = 0; k < KC; ++k) {
    uint32_t bits = rand_bits(ks0, ks1, pbase + (uint32_t)k);
    float f = __uint_as_float((bits >> 9) | 0x3f800000u) - 1.0f;
    float u = (f > 0.0f) ? f : TINY;
    float g = -logf(-logf(u));
    float v = g + xs[k];
    if (v > best_v) { best_v = v; best_k = k; }
    xmax = fmaxf(xmax, xs[k]);
  }
  float s = 0.0f;
#pragma unroll
  for (int k = 0; k < KC; ++k) s += expf(xs[k] - xmax);
  slp[gid] = (xs[best_k] - xmax) - logf(s);
  assign[gid] = (uint8_t)best_k;
}

// ---------------------------------------------------------------------------
// Kernel A: lp reduction + stable grouping + capacity split + route table.
// One block per instance.
// ---------------------------------------------------------------------------
__global__ __launch_bounds__(256) void k_prep(
    const float* __restrict__ coords,    // (64,1001,2)
    const float* __restrict__ demands,   // (64,1001)
    const float* __restrict__ capacity,  // (64,)
    const uint8_t* __restrict__ assign,  // (64,1000)
    const float* __restrict__ slp,       // (64,1000)
    float2* __restrict__ gxy,            // (64,1000) member order
    uint32_t* __restrict__ groutes,      // (64,MAXR) start<<16|len
    int* __restrict__ rcount,            // (64,)
    double* __restrict__ lp) {           // (64,)
  int b = blockIdx.x;
  int tid = threadIdx.x;
  int lane = tid & 63, wave = tid >> 6;

  __shared__ float memx[NC], memy[NC], memd[NC];
  __shared__ uint16_t rs_[NC], rl_[NC];
  __shared__ int wsum[4][KC];
  __shared__ int mc[KC], mbase[KC], rc[KC], rbase[KC];
  __shared__ double red[256];

  // ---- 1. lp reduction (same order as previous rounds -> bit-identical) ----
  double lacc = 0.0;
  for (int n = tid; n < NC; n += 256) lacc += (double)slp[(size_t)b * NC + n];
  red[tid] = lacc;
  __syncthreads();
  for (int off = 128; off > 0; off >>= 1) {
    if (tid < off) red[tid] += red[tid + off];
    __syncthreads();
  }
  if (tid == 0) lp[b] = red[0];

  // ---- 2. per-thread chunk of 4 customers (GUARDED: tid 250..255 idle) ----
  int i0 = tid * 4;
  bool valid = (i0 < NC);                 // NC % 4 == 0: chunk all-in or all-out
  int a0 = 0xFF, a1 = 0xFF, a2 = 0xFF, a3 = 0xFF;
  float x0f = 0, y0f = 0, d0f = 0, x1f = 0, y1f = 0, d1f = 0;
  float x2f = 0, y2f = 0, d2f = 0, x3f = 0, y3f = 0, d3f = 0;
  if (valid) {
    const float* cb = coords + (size_t)b * 1001 * 2;
    const float* db = demands + (size_t)b * 1001;
    uchar4 av = *(const uchar4*)(assign + (size_t)b * NC + i0);
    a0 = av.x; a1 = av.y; a2 = av.z; a3 = av.w;
    x0f = cb[(i0 + 1) * 2]; y0f = cb[(i0 + 1) * 2 + 1]; d0f = db[i0 + 1];
    x1f = cb[(i0 + 2) * 2]; y1f = cb[(i0 + 2) * 2 + 1]; d1f = db[i0 + 2];
    x2f = cb[(i0 + 3) * 2]; y2f = cb[(i0 + 3) * 2 + 1]; d2f = db[i0 + 3];
    x3f = cb[(i0 + 4) * 2]; y3f = cb[(i0 + 4) * 2 + 1]; d3f = db[i0 + 4];
  }
  int cnt[KC], excl[KC];
#pragma unroll
  for (int k = 0; k < KC; ++k)
    cnt[k] = (a0 == k) + (a1 == k) + (a2 == k) + (a3 == k);

  // ---- 3. parallel exclusive prefix per cluster ----
#pragma unroll
  for (int k = 0; k < KC; ++k) {
    int x = cnt[k];
#pragma unroll
    for (int off = 1; off < 64; off <<= 1) {
      int v = __shfl_up(x, off);
      if (lane >= off) x += v;
    }
    if (lane == 63) wsum[wave][k] = x;
    excl[k] = x - cnt[k];
  }
  __syncthreads();
  if (tid == 0) {
    int s = 0;
    for (int k = 0; k < KC; ++k) {
      int t = wsum[0][k] + wsum[1][k] + wsum[2][k] + wsum[3][k];
      mc[k] = t; mbase[k] = s; s += t;
    }
  }
  __syncthreads();
#pragma unroll
  for (int k = 0; k < KC; ++k) {
    int base = mbase[k];
    for (int w = 0; w < wave; ++w) base += wsum[w][k];
    excl[k] += base;
  }

  // ---- 4. stable scatter into member order ----
  if (valid) {
#pragma unroll
    for (int k = 0; k < KC; ++k) {
      int pos = excl[k];
      if (a0 == k) { memx[pos] = x0f; memy[pos] = y0f; memd[pos] = d0f; pos++; }
      if (a1 == k) { memx[pos] = x1f; memy[pos] = y1f; memd[pos] = d1f; pos++; }
      if (a2 == k) { memx[pos] = x2f; memy[pos] = y2f; memd[pos] = d2f; pos++; }
      if (a3 == k) { memx[pos] = x3f; memy[pos] = y3f; memd[pos] = d3f; pos++; }
    }
  }
  __syncthreads();

  // ---- 5a. publish member-order coords ----
  for (int i = tid; i < NC; i += 256)
    gxy[(size_t)b * NC + i] = make_float2(memx[i], memy[i]);

  // ---- 5b. capacity split per cluster (exact f32 scan semantics) ----
  float cap = capacity[b];
  if (tid < KC) {
    int base = mbase[tid], M = mc[tid];
    int r = 0, cur = 0;
    float load = 0.0f;
    bool ne = false;
    for (int j0 = 0; j0 < M; j0 += 4) {
      float dd0 = memd[base + j0];
      float dd1 = (j0 + 1 < M) ? memd[base + j0 + 1] : 0.0f;
      float dd2 = (j0 + 2 < M) ? memd[base + j0 + 2] : 0.0f;
      float dd3 = (j0 + 3 < M) ? memd[base + j0 + 3] : 0.0f;
#define SPLIT_STEP(dd, jj)                                                    \
      if (j0 + jj < M) {                                                      \
        float d = dd;                                                         \
        if (ne && (load + d > cap)) {                                         \
          rs_[base + r] = (uint16_t)cur; rl_[base + r] = (uint16_t)(j0 + jj - cur); \
          r++; cur = j0 + jj; load = d;                                       \
        } else load += d;                                                     \
        ne = true;                                                            \
      }
      SPLIT_STEP(dd0, 0) SPLIT_STEP(dd1, 1) SPLIT_STEP(dd2, 2) SPLIT_STEP(dd3, 3)
#undef SPLIT_STEP
    }
    if (ne) { rs_[base + r] = (uint16_t)cur; rl_[base + r] = (uint16_t)(M - cur); r++; }
    rc[tid] = r;
  }
  __syncthreads();
  if (tid == 0) {
    int s = 0;
    for (int k = 0; k < KC; ++k) { rbase[k] = s; s += rc[k]; }
    rcount[b] = (s < MAXR) ? s : MAXR;
  }
  __syncthreads();

  // ---- 6. compact route table to global ----
  if (tid < KC) {
    int k = tid, base = mbase[k];
    for (int r = 0; r < rc[k]; ++r) {
      int slot = rbase[k] + r;
      if (slot < MAXR)
        groutes[(size_t)b * MAXR + slot] =
            ((uint32_t)(base + rs_[base + r]) << 16) | (uint32_t)rl_[base + r];
    }
  }
}

// ---------------------------------------------------------------------------
// Kernel B: one 16-LANE GROUP per route (up to 64 members = 4 chunks of 16),
// members in registers, 4-step shfl_xor packed-min argmin (masks stay inside
// the group). Identical winner + f32 accumulation order vs reference scan.
// P(route > 64 members) = P(sum of 64 U[0,1] <= 5) = 5^64/64! ~ 4e-45 -> safe.
// ---------------------------------------------------------------------------
__global__ __launch_bounds__(256) void k_nn(
    const float* __restrict__ coords,     // (64,1001,2) for depot
    const float2* __restrict__ gxy,       // (64,1000) member order
    const uint32_t* __restrict__ groutes, // (64,MAXR)
    const int* __restrict__ rcount,       // (64,)
    float* __restrict__ rdist) {          // (64,MAXR)
  int b = blockIdx.x / WPB_B;
  int sb = blockIdx.x % WPB_B;
  int lane = threadIdx.x & 63;            // lane within wave
  int lane16 = threadIdx.x & 15;          // lane within group
  int gbase = lane & 0x30;                // group base lane within wave
  int g = sb * 16 + (threadIdx.x >> 4);   // global group id within instance

  float dx0 = coords[(size_t)b * 1001 * 2];
  float dy0 = coords[(size_t)b * 1001 * 2 + 1];
  int R = rcount[b];

  for (int r = g; r < R; r += WPB_B * 16) {
    uint32_t pk = groutes[(size_t)b * MAXR + r];
    int start = (int)(pk >> 16);
    int L = (int)(pk & 0xFFFFu);

    // lane16 j holds member slots j, j+16, j+32, j+48 (slot order = index order)
    float mx0 = 0, my0 = 0, mx1 = 0, my1 = 0, mx2 = 0, my2 = 0, mx3 = 0, my3 = 0;
    uint32_t vis = 0;
#define LOADC(c, MX, MY)                                                      \
    { int s = (c) * 16 + lane16;                                              \
      if (s < L) { float2 v = gxy[(size_t)b * NC + start + s]; MX = v.x; MY = v.y; } \
      else vis |= (1u << (c)); }
    LOADC(0, mx0, my0) LOADC(1, mx1, my1) LOADC(2, mx2, my2) LOADC(3, mx3, my3)
#undef LOADC

    float px = dx0, py = dy0, racc = 0.0f;
    for (int step = 0; step < L; ++step) {
      float bd = INFINITY; int bc = -1;
#define CAND(c, MX, MY)                                                       \
      if (!(vis & (1u << (c)))) {                                             \
        float ddx = MX - px, ddy = MY - py;                                   \
        float d = sqrtf(ddx * ddx + ddy * ddy);                               \
        if (d < bd) { bd = d; bc = (c); }                                     \
      }
      CAND(0, mx0, my0) CAND(1, mx1, my1) CAND(2, mx2, my2) CAND(3, mx3, my3)
#undef CAND
      unsigned long long comb = (bc < 0)
          ? ~0ull
          : (((unsigned long long)__float_as_uint(bd)) << 32) |
            (unsigned)(bc * 16 + lane16);
#pragma unroll
      for (int m = 1; m < 16; m <<= 1) {          // stays within 16-lane group
        unsigned long long o = __shfl_xor(comb, m);
        comb = (o < comb) ? o : comb;
      }
      int slot = (int)(comb & 0xFFFFFFFFull);     // 0..63 within route
      float best = __uint_as_float((uint32_t)(comb >> 32));
      int src16 = slot & 15, cu = slot >> 4;      // group-uniform
      if (src16 == lane16) vis |= (1u << cu);
      float cx, cy;
      switch (cu) {
        case 0: cx = mx0; cy = my0; break;
        case 1: cx = mx1; cy = my1; break;
        case 2: cx = mx2; cy = my2; break;
        default: cx = mx3; cy = my3; break;
      }
      px = __shfl(cx, gbase + src16);
      py = __shfl(cy, gbase + src16);
      racc += best;                     // f32, step order == reference scan order
    }
    float ddx = px - dx0, ddy = py - dy0;
    racc += sqrtf(ddx * ddx + ddy * ddy);   // return-to-depot leg
    if (lane16 == 0) rdist[(size_t)b * MAXR + r] = racc;
  }
}

// ---------------------------------------------------------------------------
// Kernel C: per-instance route-distance sum + baseline + REINFORCE loss
// ---------------------------------------------------------------------------
__global__ __launch_bounds__(64) void k_final(
    const double* __restrict__ lp,
    const float* __restrict__ rdist,
    const int* __restrict__ rcount,
    float* __restrict__ out) {
  __shared__ double sdist[BB];
  int tid = threadIdx.x;
  {
    int R = rcount[tid];
    const float* rd = rdist + (size_t)tid * MAXR;
    double s0 = 0, s1 = 0, s2 = 0, s3 = 0;
    int r = 0;
    for (; r + 4 <= R; r += 4) {
      s0 += (double)rd[r + 0]; s1 += (double)rd[r + 1];
      s2 += (double)rd[r + 2]; s3 += (double)rd[r + 3];
    }
    for (; r < R; ++r) s0 += (double)rd[r];
    sdist[tid] = (s0 + s1) + (s2 + s3);
  }
  __syncthreads();
  if (tid == 0) {
    float df[BB], lf[BB];
    double sum = 0.0;
    for (int i = 0; i < BB; ++i) {
      df[i] = (float)sdist[i];
      lf[i] = (float)lp[i];
      sum += (double)df[i];
    }
    double mean = sum / (double)BB;
    float meanf = (float)mean;
    double loss = 0.0;
    for (int i = 0; i < BB; ++i)
      loss += ((double)df[i] - (double)meanf) * (double)lf[i];
    loss /= (double)BB;
    out[0] = (float)loss;
    out[1] = (float)mean;
  }
}

extern "C" void kernel_launch(void* const* d_in, const int* in_sizes, int n_in,
                              void* d_out, int out_size, void* d_ws, size_t ws_size,
                              hipStream_t stream) {
  const float* logits   = (const float*)d_in[0];  // (64,1001,10)
  const float* coords   = (const float*)d_in[1];  // (64,1001,2)
  const float* demands  = (const float*)d_in[2];  // (64,1001)
  const float* capacity = (const float*)d_in[3];  // (64,)

  uint8_t* ws = (uint8_t*)d_ws;
  float2*   gxy     = (float2*)(ws);                  // 512000 B
  float*    rdist   = (float*)(ws + 512000);          // 131072 B
  uint32_t* groutes = (uint32_t*)(ws + 643072);       // 131072 B
  int*      rcount  = (int*)(ws + 774144);            // 256 B
  double*   lp      = (double*)(ws + 774400);         // 512 B
  uint8_t*  assign  = (uint8_t*)(ws + 774912);        // 64000 B
  float*    slp     = (float*)(ws + 838912);          // 256000 B

  uint32_t ks0, ks1;
  threefry2x32(0u, 42u, 0u, 0u, &ks0, &ks1);   // fold_in(key(42), 0)

  k_sample<<<dim3((BB * NC + 255) / 256), dim3(256), 0, stream>>>(
      logits, ks0, ks1, assign, slp);
  k_prep<<<dim3(BB), dim3(256), 0, stream>>>(coords, demands, capacity,
                                             assign, slp, gxy, groutes, rcount, lp);
  k_nn<<<dim3(BB * WPB_B), dim3(256), 0, stream>>>(coords, gxy, groutes, rcount, rdist);
  k_final<<<dim3(1), dim3(64), 0, stream>>>(lp, rdist, rcount, (float*)d_out);
}

// Round 6
// 42.067 us; speedup vs baseline: 7.2047x; 1.1296x over previous
//
#include <hip/hip_runtime.h>
#include <stdint.h>

#define BB 64
#define NC 1000       // customers per instance
#define KC 10         // clusters
#define MAXR 512      // routes per instance upper bound (realistic max ~140)
#define WPB_B 16      // blocks per instance in fused kernel (16 groups each)

__host__ __device__ inline void threefry2x32(uint32_t k0, uint32_t k1,
                                             uint32_t x0, uint32_t x1,
                                             uint32_t* o0, uint32_t* o1) {
  uint32_t k2 = k0 ^ k1 ^ 0x1BD11BDAu;
  x0 += k0; x1 += k1;
#define TF_R(R) { x0 += x1; x1 = (x1 << (R)) | (x1 >> (32 - (R))); x1 ^= x0; }
  TF_R(13) TF_R(15) TF_R(26) TF_R(6)
  x0 += k1; x1 += k2 + 1u;
  TF_R(17) TF_R(29) TF_R(16) TF_R(24)
  x0 += k2; x1 += k0 + 2u;
  TF_R(13) TF_R(15) TF_R(26) TF_R(6)
  x0 += k0; x1 += k1 + 3u;
  TF_R(17) TF_R(29) TF_R(16) TF_R(24)
  x0 += k1; x1 += k2 + 4u;
  TF_R(13) TF_R(15) TF_R(26) TF_R(6)
  x0 += k2; x1 += k0 + 5u;
#undef TF_R
  *o0 = x0; *o1 = x1;
}

__device__ inline uint32_t rand_bits(uint32_t ks0, uint32_t ks1, uint32_t p) {
  uint32_t a, b; threefry2x32(ks0, ks1, 0u, p, &a, &b); return b;
}

// DPP 16-lane argmin butterfly step. CTRL patterns (within one 16-lane row):
// 0xB1 quad_perm[1,0,3,2] = lane^1; 0x4E quad_perm[2,3,0,1] = lane^2;
// 0x141 row_half_mirror = lane^7 (== xor4 once quads uniform);
// 0x140 row_mirror = lane^15 (== xor8 once 8-groups uniform).
// Each 16-lane group is exactly one DPP row and is branch-uniform, so all
// source lanes are active.
template <int CTRL>
__device__ __forceinline__ void dpp_min_step(unsigned long long& comb,
                                             float& x, float& y) {
  int lo = (int)(uint32_t)comb;
  int hi = (int)(uint32_t)(comb >> 32);
  int olo = __builtin_amdgcn_update_dpp(lo, lo, CTRL, 0xf, 0xf, false);
  int ohi = __builtin_amdgcn_update_dpp(hi, hi, CTRL, 0xf, 0xf, false);
  int oxi = __builtin_amdgcn_update_dpp(__float_as_int(x), __float_as_int(x),
                                        CTRL, 0xf, 0xf, false);
  int oyi = __builtin_amdgcn_update_dpp(__float_as_int(y), __float_as_int(y),
                                        CTRL, 0xf, 0xf, false);
  unsigned long long o =
      ((unsigned long long)(uint32_t)ohi << 32) | (uint32_t)olo;
  if (o < comb) { comb = o; x = __int_as_float(oxi); y = __int_as_float(oyi); }
}

// ---------------------------------------------------------------------------
// Kernel S: one thread per customer — gumbel-argmax sample + logprob.
// ---------------------------------------------------------------------------
__global__ __launch_bounds__(256) void k_sample(
    const float* __restrict__ logits,   // (64,1001,10)
    uint32_t ks0, uint32_t ks1,
    uint8_t* __restrict__ assign,       // (64,1000)
    float* __restrict__ slp) {          // (64,1000)
  int gid = blockIdx.x * 256 + threadIdx.x;
  if (gid >= BB * NC) return;
  int b = gid / NC, n = gid - b * NC;
  const float TINY = 1.1754943508222875e-38f;

  const float* lrow = logits + ((size_t)b * 1001 + (size_t)(n + 1)) * KC;
  float xs[KC];
#pragma unroll
  for (int k = 0; k < KC; ++k) xs[k] = lrow[k];
  uint32_t pbase = (uint32_t)gid * (uint32_t)KC;
  int best_k = 0;
  float best_v = -INFINITY;
  float xmax = -INFINITY;
#pragma unroll
  for (int k = 0; k < KC; ++k) {
    uint32_t bits = rand_bits(ks0, ks1, pbase + (uint32_t)k);
    float f = __uint_as_float((bits >> 9) | 0x3f800000u) - 1.0f;
    float u = (f > 0.0f) ? f : TINY;
    float g = -logf(-logf(u));
    float v = g + xs[k];
    if (v > best_v) { best_v = v; best_k = k; }
    xmax = fmaxf(xmax, xs[k]);
  }
  float s = 0.0f;
#pragma unroll
  for (int k = 0; k < KC; ++k) s += expf(xs[k] - xmax);
  slp[gid] = (xs[best_k] - xmax) - logf(s);
  assign[gid] = (uint8_t)best_k;
}

// ---------------------------------------------------------------------------
// Kernel F: fused prep (redundant per block) + NN. 16 blocks per instance;
// each block rebuilds the instance's member order + route table in LDS
// (deterministic: identical inputs -> identical results), then its 16
// 16-lane groups each run one NN route entirely in registers/LDS.
// Block sb==0 additionally reduces lp and writes rcount.
// ---------------------------------------------------------------------------
__global__ __launch_bounds__(256) void k_fused(
    const float* __restrict__ coords,    // (64,1001,2)
    const float* __restrict__ demands,   // (64,1001)
    const float* __restrict__ capacity,  // (64,)
    const uint8_t* __restrict__ assign,  // (64,1000)
    const float* __restrict__ slp,       // (64,1000)
    float* __restrict__ rdist,           // (64,MAXR)
    int* __restrict__ rcount,            // (64,)
    double* __restrict__ lp) {           // (64,)
  int b = blockIdx.x / WPB_B;
  int sb = blockIdx.x % WPB_B;
  int tid = threadIdx.x;
  int lane = tid & 63, wave = tid >> 6;

  __shared__ float memx[NC], memy[NC], memd[NC];
  __shared__ uint16_t rs_[NC], rl_[NC];
  __shared__ uint32_t grt[MAXR];        // compact route table: start<<16|len
  __shared__ int wsum[4][KC];
  __shared__ int mc[KC], mbase[KC], rc[KC], rbase[KC];
  __shared__ int rtot_s;
  __shared__ double red[256];

  // ---- lp reduction (sb==0 only; block-uniform branch) ----
  if (sb == 0) {
    double lacc = 0.0;
    for (int n = tid; n < NC; n += 256) lacc += (double)slp[(size_t)b * NC + n];
    red[tid] = lacc;
    __syncthreads();
    for (int off = 128; off > 0; off >>= 1) {
      if (tid < off) red[tid] += red[tid + off];
      __syncthreads();
    }
    if (tid == 0) lp[b] = red[0];
  }

  // ---- per-thread chunk of 4 customers (GUARDED: tid 250..255 idle) ----
  int i0 = tid * 4;
  bool valid = (i0 < NC);
  int a0 = 0xFF, a1 = 0xFF, a2 = 0xFF, a3 = 0xFF;
  float x0f = 0, y0f = 0, d0f = 0, x1f = 0, y1f = 0, d1f = 0;
  float x2f = 0, y2f = 0, d2f = 0, x3f = 0, y3f = 0, d3f = 0;
  if (valid) {
    const float* cb = coords + (size_t)b * 1001 * 2;
    const float* db = demands + (size_t)b * 1001;
    uchar4 av = *(const uchar4*)(assign + (size_t)b * NC + i0);
    a0 = av.x; a1 = av.y; a2 = av.z; a3 = av.w;
    x0f = cb[(i0 + 1) * 2]; y0f = cb[(i0 + 1) * 2 + 1]; d0f = db[i0 + 1];
    x1f = cb[(i0 + 2) * 2]; y1f = cb[(i0 + 2) * 2 + 1]; d1f = db[i0 + 2];
    x2f = cb[(i0 + 3) * 2]; y2f = cb[(i0 + 3) * 2 + 1]; d2f = db[i0 + 3];
    x3f = cb[(i0 + 4) * 2]; y3f = cb[(i0 + 4) * 2 + 1]; d3f = db[i0 + 4];
  }
  int cnt[KC], excl[KC];
#pragma unroll
  for (int k = 0; k < KC; ++k)
    cnt[k] = (a0 == k) + (a1 == k) + (a2 == k) + (a3 == k);

  // ---- parallel exclusive prefix per cluster ----
#pragma unroll
  for (int k = 0; k < KC; ++k) {
    int x = cnt[k];
#pragma unroll
    for (int off = 1; off < 64; off <<= 1) {
      int v = __shfl_up(x, off);
      if (lane >= off) x += v;
    }
    if (lane == 63) wsum[wave][k] = x;
    excl[k] = x - cnt[k];
  }
  __syncthreads();
  if (tid == 0) {
    int s = 0;
    for (int k = 0; k < KC; ++k) {
      int t = wsum[0][k] + wsum[1][k] + wsum[2][k] + wsum[3][k];
      mc[k] = t; mbase[k] = s; s += t;
    }
  }
  __syncthreads();
#pragma unroll
  for (int k = 0; k < KC; ++k) {
    int base = mbase[k];
    for (int w = 0; w < wave; ++w) base += wsum[w][k];
    excl[k] += base;
  }

  // ---- stable scatter into member order ----
  if (valid) {
#pragma unroll
    for (int k = 0; k < KC; ++k) {
      int pos = excl[k];
      if (a0 == k) { memx[pos] = x0f; memy[pos] = y0f; memd[pos] = d0f; pos++; }
      if (a1 == k) { memx[pos] = x1f; memy[pos] = y1f; memd[pos] = d1f; pos++; }
      if (a2 == k) { memx[pos] = x2f; memy[pos] = y2f; memd[pos] = d2f; pos++; }
      if (a3 == k) { memx[pos] = x3f; memy[pos] = y3f; memd[pos] = d3f; pos++; }
    }
  }
  __syncthreads();

  // ---- capacity split per cluster (exact f32 scan semantics) ----
  float cap = capacity[b];
  if (tid < KC) {
    int base = mbase[tid], M = mc[tid];
    int r = 0, cur = 0;
    float load = 0.0f;
    bool ne = false;
    for (int j0 = 0; j0 < M; j0 += 4) {
      float dd0 = memd[base + j0];
      float dd1 = (j0 + 1 < M) ? memd[base + j0 + 1] : 0.0f;
      float dd2 = (j0 + 2 < M) ? memd[base + j0 + 2] : 0.0f;
      float dd3 = (j0 + 3 < M) ? memd[base + j0 + 3] : 0.0f;
#define SPLIT_STEP(dd, jj)                                                    \
      if (j0 + jj < M) {                                                      \
        float d = dd;                                                         \
        if (ne && (load + d > cap)) {                                         \
          rs_[base + r] = (uint16_t)cur; rl_[base + r] = (uint16_t)(j0 + jj - cur); \
          r++; cur = j0 + jj; load = d;                                       \
        } else load += d;                                                     \
        ne = true;                                                            \
      }
      SPLIT_STEP(dd0, 0) SPLIT_STEP(dd1, 1) SPLIT_STEP(dd2, 2) SPLIT_STEP(dd3, 3)
#undef SPLIT_STEP
    }
    if (ne) { rs_[base + r] = (uint16_t)cur; rl_[base + r] = (uint16_t)(M - cur); r++; }
    rc[tid] = r;
  }
  __syncthreads();
  if (tid == 0) {
    int s = 0;
    for (int k = 0; k < KC; ++k) { rbase[k] = s; s += rc[k]; }
    rtot_s = (s < MAXR) ? s : MAXR;
    if (sb == 0) rcount[b] = rtot_s;
  }
  __syncthreads();

  // ---- compact route table into LDS ----
  if (tid < KC) {
    int k = tid, base = mbase[k];
    for (int r = 0; r < rc[k]; ++r) {
      int slot = rbase[k] + r;
      if (slot < MAXR)
        grt[slot] =
            ((uint32_t)(base + rs_[base + r]) << 16) | (uint32_t)rl_[base + r];
    }
  }
  __syncthreads();

  // ---- NN: one 16-lane group per route, members in registers ----
  int lane16 = tid & 15;
  int g = sb * 16 + (tid >> 4);
  int R = rtot_s;
  float dx0 = coords[(size_t)b * 1001 * 2];
  float dy0 = coords[(size_t)b * 1001 * 2 + 1];

  for (int r = g; r < R; r += WPB_B * 16) {
    uint32_t pk = grt[r];
    int start = (int)(pk >> 16);
    int L = (int)(pk & 0xFFFFu);

    // lane16 j holds member slots j, j+16, j+32, j+48 (slot order = index order)
    float mx0 = 0, my0 = 0, mx1 = 0, my1 = 0, mx2 = 0, my2 = 0, mx3 = 0, my3 = 0;
    uint32_t vis = 0;
#define LOADC(c, MX, MY)                                                      \
    { int s = (c) * 16 + lane16;                                              \
      if (s < L) { MX = memx[start + s]; MY = memy[start + s]; }              \
      else vis |= (1u << (c)); }
    LOADC(0, mx0, my0) LOADC(1, mx1, my1) LOADC(2, mx2, my2) LOADC(3, mx3, my3)
#undef LOADC

    float px = dx0, py = dy0, racc = 0.0f;
    for (int step = 0; step < L; ++step) {
      float bd = INFINITY; int bc = -1; float bx = 0, by = 0;
#define CAND(c, MX, MY)                                                       \
      if (!(vis & (1u << (c)))) {                                             \
        float ddx = MX - px, ddy = MY - py;                                   \
        float d = sqrtf(ddx * ddx + ddy * ddy);                               \
        if (d < bd) { bd = d; bc = (c); bx = MX; by = MY; }                   \
      }
      CAND(0, mx0, my0) CAND(1, mx1, my1) CAND(2, mx2, my2) CAND(3, mx3, my3)
#undef CAND
      // packed key: dist bits (IEEE order for non-negative) || slot index.
      unsigned long long comb = (bc < 0)
          ? ~0ull
          : (((unsigned long long)__float_as_uint(bd)) << 32) |
            (unsigned)(bc * 16 + lane16);
      // 16-lane DPP butterfly min; carries winner's (x,y) along.
      dpp_min_step<0xB1>(comb, bx, by);    // lane^1
      dpp_min_step<0x4E>(comb, bx, by);    // lane^2
      dpp_min_step<0x141>(comb, bx, by);   // half mirror (xor4 effective)
      dpp_min_step<0x140>(comb, bx, by);   // mirror (xor8 effective)
      int slot = (int)(comb & 0xFFFFFFFFull);   // 0..63 within route
      float best = __uint_as_float((uint32_t)(comb >> 32));
      int src16 = slot & 15, cu = slot >> 4;
      if (src16 == lane16) vis |= (1u << cu);
      px = bx; py = by;                    // winner coords (all lanes uniform)
      racc += best;                        // f32, step order == reference scan
    }
    float ddx = px - dx0, ddy = py - dy0;
    racc += sqrtf(ddx * ddx + ddy * ddy);  // return-to-depot leg
    if (lane16 == 0) rdist[(size_t)b * MAXR + r] = racc;
  }
}

// ---------------------------------------------------------------------------
// Kernel C: per-instance route-distance sum + baseline + REINFORCE loss.
// 4 threads per instance for the rdist sums (same mod-4 partition as before),
// then 64-lane butterfly double reductions.
// ---------------------------------------------------------------------------
__global__ __launch_bounds__(256) void k_final(
    const double* __restrict__ lp,
    const float* __restrict__ rdist,
    const int* __restrict__ rcount,
    float* __restrict__ out) {
  __shared__ double psum[256];
  int tid = threadIdx.x;
  int inst = tid >> 2, sub = tid & 3;
  {
    int R = rcount[inst];
    const float* rd = rdist + (size_t)inst * MAXR;
    double s = 0.0;
    for (int r = sub; r < R; r += 4) s += (double)rd[r];
    psum[tid] = s;
  }
  __syncthreads();
  if (tid < 64) {
    double dd = psum[4 * tid] + psum[4 * tid + 1] +
                psum[4 * tid + 2] + psum[4 * tid + 3];
    float df = (float)dd;
    float lf = (float)lp[tid];
    double m = (double)df;
#pragma unroll
    for (int m2 = 1; m2 < 64; m2 <<= 1) m += __shfl_xor(m, m2);
    double mean = m / 64.0;
    float meanf = (float)mean;
    double li = ((double)df - (double)meanf) * (double)lf;
#pragma unroll
    for (int m2 = 1; m2 < 64; m2 <<= 1) li += __shfl_xor(li, m2);
    if (tid == 0) {
      out[0] = (float)(li / 64.0);
      out[1] = meanf;
    }
  }
}

extern "C" void kernel_launch(void* const* d_in, const int* in_sizes, int n_in,
                              void* d_out, int out_size, void* d_ws, size_t ws_size,
                              hipStream_t stream) {
  const float* logits   = (const float*)d_in[0];  // (64,1001,10)
  const float* coords   = (const float*)d_in[1];  // (64,1001,2)
  const float* demands  = (const float*)d_in[2];  // (64,1001)
  const float* capacity = (const float*)d_in[3];  // (64,)

  uint8_t* ws = (uint8_t*)d_ws;
  float*   rdist  = (float*)(ws);                 // 131072 B
  double*  lp     = (double*)(ws + 131072);       // 512 B
  int*     rcount = (int*)(ws + 131584);          // 256 B
  uint8_t* assign = (uint8_t*)(ws + 131840);      // 64000 B
  float*   slp    = (float*)(ws + 195840);        // 256000 B

  uint32_t ks0, ks1;
  threefry2x32(0u, 42u, 0u, 0u, &ks0, &ks1);   // fold_in(key(42), 0)

  k_sample<<<dim3((BB * NC + 255) / 256), dim3(256), 0, stream>>>(
      logits, ks0, ks1, assign, slp);
  k_fused<<<dim3(BB * WPB_B), dim3(256), 0, stream>>>(
      coords, demands, capacity, assign, slp, rdist, rcount, lp);
  k_final<<<dim3(1), dim3(256), 0, stream>>>(lp, rdist, rcount, (float*)d_out);
}